// Round 9
// baseline (456.565 us; speedup 1.0000x reference)
//
#include <hip/hip_runtime.h>
#include <hip/hip_bf16.h>

// Flash-attention forward, B=4 H=16 S=2048 D=128, fp32 in/out, no 1/sqrt(D) scale.
// Round 8: occupancy 3->4 blocks/CU. LDS 43008 -> 40960 B exactly:
//   - K: padded [64][136] -> linear [64][128] + T2 XOR swizzle (col ^ ((row&7)<<3))
//   - P: PPAD 72 -> 64 (the existing ^(g<<3) swizzle already kills conflicts)
//   Keeps R7's XCD-gather block swizzle + setprio + tr_read V path.

#define QBLK   64
#define KVBLK  64
#define DHEAD  128
#define SEQ    2048
#define PPAD   64

typedef _Float16 f16x8 __attribute__((ext_vector_type(8)));
typedef _Float16 f16x4 __attribute__((ext_vector_type(4)));
typedef float    f32x4 __attribute__((ext_vector_type(4)));

__global__ __launch_bounds__(256, 4)
void attn_fwd_kernel(const float* __restrict__ Q, const float* __restrict__ K,
                     const float* __restrict__ V, float* __restrict__ O) {
    __shared__ __align__(16) _Float16 K_lds[KVBLK * DHEAD];   // linear + XOR swizzle
    __shared__ __align__(16) _Float16 V_lds[KVBLK * DHEAD];   // subtiled [kv/4][d/16][4][16]
    __shared__ __align__(16) _Float16 P_lds[4 * 16 * PPAD];

    const int tid  = threadIdx.x;
    const int lane = tid & 63;
    const int wave = tid >> 6;
    const int g    = lane >> 4;   // lane-group 0..3
    const int lg   = lane & 15;

    // ---- XCD-gather swizzle: each XCD gets 8 whole heads (all their q-tiles).
    const int flat    = blockIdx.x + gridDim.x * blockIdx.y;   // 0..2047
    const int newflat = (flat & 7) * 256 + (flat >> 3);        // bijective (2048 = 8*256)
    const int qtile   = newflat & 31;
    const int bh      = newflat >> 5;

    const size_t base = (size_t)bh * SEQ * DHEAD;
    const float* Qg = Q + base + (size_t)(qtile * QBLK) * DHEAD;
    const float* Kg = K + base;
    const float* Vg = V + base;
    float*       Og = O + base + (size_t)(qtile * QBLK) * DHEAD;

    // per-lane base byte-address for ds_read_b64_tr_b16 on V_lds:
    //   window (128B subtile) = kt*8192 + g*2048 + s*1024 + dt*128  (via offset:)
    //   column within window  = lg  -> lane-offset lg*8 bytes
    const unsigned trbase = (unsigned)(size_t)&V_lds[0] + (unsigned)(g * 2048 + lg * 8);

    // ---- Q fragments in registers (fp16). A-layout: row=lane&15, k=(lane>>4)*8+i
    f16x8 qf[4];
    {
        const float* qrow = Qg + (size_t)(wave * 16 + lg) * DHEAD;
        #pragma unroll
        for (int dc = 0; dc < 4; ++dc) {
            const int d0 = dc * 32 + g * 8;
            float4 f0 = *(const float4*)(qrow + d0);
            float4 f1 = *(const float4*)(qrow + d0 + 4);
            qf[dc][0] = (_Float16)f0.x; qf[dc][1] = (_Float16)f0.y;
            qf[dc][2] = (_Float16)f0.z; qf[dc][3] = (_Float16)f0.w;
            qf[dc][4] = (_Float16)f1.x; qf[dc][5] = (_Float16)f1.y;
            qf[dc][6] = (_Float16)f1.z; qf[dc][7] = (_Float16)f1.w;
        }
    }

    // ---- online-softmax state + output accumulators
    f32x4 acc[8];
    #pragma unroll
    for (int dt = 0; dt < 8; ++dt) { acc[dt][0]=0.f; acc[dt][1]=0.f; acc[dt][2]=0.f; acc[dt][3]=0.f; }
    float m[4], l[4];
    #pragma unroll
    for (int r = 0; r < 4; ++r) { m[r] = -1e30f; l[r] = 0.f; }

    for (int t = 0; t < SEQ / KVBLK; ++t) {
        // ---- stage K tile (linear rows + XOR swizzle; reads/writes <=2-way)
        {
            const float* Kt = Kg + (size_t)t * KVBLK * DHEAD;
            #pragma unroll
            for (int j = 0; j < 4; ++j) {
                const int c   = tid + 256 * j;      // 0..1023
                const int row = c >> 4;
                const int dc  = (c & 15) * 8;
                float4 f0 = *(const float4*)(Kt + row * DHEAD + dc);
                float4 f1 = *(const float4*)(Kt + row * DHEAD + dc + 4);
                f16x8 vh;
                vh[0]=(_Float16)f0.x; vh[1]=(_Float16)f0.y; vh[2]=(_Float16)f0.z; vh[3]=(_Float16)f0.w;
                vh[4]=(_Float16)f1.x; vh[5]=(_Float16)f1.y; vh[6]=(_Float16)f1.z; vh[7]=(_Float16)f1.w;
                *(f16x8*)&K_lds[row * 128 + (dc ^ ((row & 7) << 3))] = vh;
            }
            // ---- stage V tile into subtiled layout [kv/4][d/16][4][16]
            const float* Vt = Vg + (size_t)t * KVBLK * DHEAD;
            #pragma unroll
            for (int j = 0; j < 4; ++j) {
                const int c   = tid + 256 * j;                 // 0..1023
                const int d8  = (c & 1) | (((c >> 3) & 7) << 1);   // 0..15
                const int row = ((c >> 1) & 3) | ((c >> 6) << 2);  // 0..63
                const int d0  = d8 * 8;
                float4 f0 = *(const float4*)(Vt + row * DHEAD + d0);
                float4 f1 = *(const float4*)(Vt + row * DHEAD + d0 + 4);
                f16x8 vv;
                vv[0]=(_Float16)f0.x; vv[1]=(_Float16)f0.y; vv[2]=(_Float16)f0.z; vv[3]=(_Float16)f0.w;
                vv[4]=(_Float16)f1.x; vv[5]=(_Float16)f1.y; vv[6]=(_Float16)f1.z; vv[7]=(_Float16)f1.w;
                const int st = (row >> 2) * 8 + (d0 >> 4);
                *(f16x8*)&V_lds[st * 64 + (row & 3) * 16 + (d0 & 15)] = vv;
            }
        }
        __syncthreads();

        // ---- S = Q * K^T (16 q-rows x 64 kv-cols per wave)
        f32x4 s[4];
        __builtin_amdgcn_s_setprio(1);
        #pragma unroll
        for (int ct = 0; ct < 4; ++ct) {
            f32x4 a; a[0]=0.f; a[1]=0.f; a[2]=0.f; a[3]=0.f;
            #pragma unroll
            for (int dc = 0; dc < 4; ++dc) {
                const int krow = ct * 16 + lg;
                const int off  = krow * 128 + ((dc * 32 + g * 8) ^ ((krow & 7) << 3));
                f16x8 kh = *(const f16x8*)&K_lds[off];
                a = __builtin_amdgcn_mfma_f32_16x16x32_f16(qf[dc], kh, a, 0, 0, 0);
            }
            s[ct] = a;
        }
        __builtin_amdgcn_s_setprio(0);

        // ---- online softmax (per q-row r; row lives in 16-lane group)
        #pragma unroll
        for (int r = 0; r < 4; ++r) {
            float rowmax = fmaxf(fmaxf(s[0][r], s[1][r]), fmaxf(s[2][r], s[3][r]));
            #pragma unroll
            for (int off = 1; off < 16; off <<= 1)
                rowmax = fmaxf(rowmax, __shfl_xor(rowmax, off));
            const float mnew = fmaxf(m[r], rowmax);
            const float sc   = __expf(m[r] - mnew);
            m[r] = mnew;
            float rs = 0.f;
            #pragma unroll
            for (int ct = 0; ct < 4; ++ct) {
                float p = __expf(s[ct][r] - mnew);
                s[ct][r] = p;
                rs += p;
            }
            #pragma unroll
            for (int off = 1; off < 16; off <<= 1)
                rs += __shfl_xor(rs, off);
            l[r] = l[r] * sc + rs;
            #pragma unroll
            for (int dt = 0; dt < 8; ++dt) acc[dt][r] *= sc;
        }

        // ---- P (C/D layout) -> LDS (XOR-swizzled) -> A-fragment layout
        _Float16* pbase = &P_lds[wave * 16 * PPAD];
        #pragma unroll
        for (int ct = 0; ct < 4; ++ct)
            #pragma unroll
            for (int r = 0; r < 4; ++r)
                pbase[(g * 4 + r) * PPAD + ((ct * 16 + lg) ^ (g << 3))] = (_Float16)s[ct][r];

        // ---- O += P * V  (V via ds_read_b64_tr_b16 from subtiled layout)
        #pragma unroll
        for (int kt = 0; kt < 2; ++kt) {
            f16x8 pf = *(const f16x8*)&pbase[lg * PPAD + ((kt * 32 + g * 8) ^ ((lg >> 2) << 3))];
            #pragma unroll
            for (int dp = 0; dp < 4; ++dp) {
                f16x4 a0, a1, b0, b1;
                asm volatile(
                    "ds_read_b64_tr_b16 %0, %4 offset:%5\n\t"
                    "ds_read_b64_tr_b16 %1, %4 offset:%6\n\t"
                    "ds_read_b64_tr_b16 %2, %4 offset:%7\n\t"
                    "ds_read_b64_tr_b16 %3, %4 offset:%8\n\t"
                    "s_waitcnt lgkmcnt(0)"
                    : "=&v"(a0), "=&v"(a1), "=&v"(b0), "=&v"(b1)
                    : "v"(trbase),
                      "i"(kt * 8192 + (dp * 2 + 0) * 128),
                      "i"(kt * 8192 + 1024 + (dp * 2 + 0) * 128),
                      "i"(kt * 8192 + (dp * 2 + 1) * 128),
                      "i"(kt * 8192 + 1024 + (dp * 2 + 1) * 128)
                    : "memory");
                __builtin_amdgcn_sched_barrier(0);
                f16x8 vf0 = __builtin_shufflevector(a0, a1, 0, 1, 2, 3, 4, 5, 6, 7);
                f16x8 vf1 = __builtin_shufflevector(b0, b1, 0, 1, 2, 3, 4, 5, 6, 7);
                __builtin_amdgcn_s_setprio(1);
                acc[dp * 2 + 0] = __builtin_amdgcn_mfma_f32_16x16x32_f16(pf, vf0, acc[dp * 2 + 0], 0, 0, 0);
                acc[dp * 2 + 1] = __builtin_amdgcn_mfma_f32_16x16x32_f16(pf, vf1, acc[dp * 2 + 1], 0, 0, 0);
                __builtin_amdgcn_s_setprio(0);
            }
        }
        __syncthreads();
    }

    // ---- epilogue: O / l
    float inv[4];
    #pragma unroll
    for (int r = 0; r < 4; ++r) inv[r] = 1.f / l[r];
    float* ob = Og + (size_t)(wave * 16) * DHEAD;
    #pragma unroll
    for (int dt = 0; dt < 8; ++dt)
        #pragma unroll
        for (int r = 0; r < 4; ++r)
            ob[(size_t)(g * 4 + r) * DHEAD + dt * 16 + lg] = acc[dt][r] * inv[r];
}

extern "C" void kernel_launch(void* const* d_in, const int* in_sizes, int n_in,
                              void* d_out, int out_size, void* d_ws, size_t ws_size,
                              hipStream_t stream) {
    const float* q = (const float*)d_in[0];
    const float* k = (const float*)d_in[1];
    const float* v = (const float*)d_in[2];
    float* out = (float*)d_out;
    const int BH = in_sizes[0] / (SEQ * DHEAD);   // 64
    dim3 grid(SEQ / QBLK, BH);
    attn_fwd_kernel<<<grid, dim3(256), 0, stream>>>(q, k, v, out);
}

// Round 10
// 283.534 us; speedup vs baseline: 1.6103x; 1.6103x over previous
//
#include <hip/hip_runtime.h>
#include <hip/hip_bf16.h>

// Flash-attention forward, B=4 H=16 S=2048 D=128, fp32 in/out, no 1/sqrt(D) scale.
// Round 9: revert R8's occupancy trade (spill + P-conflicts). Back to R7 layout.
//   NEW: swapped-operand QK^T -> mfma(K,Q) gives S^T, so each lane owns ONE q-row:
//   softmax reduction = 15 VALU + 2 shfl_xor (was 32 serial ds_bpermute per tile),
//   m/l scalar per lane, P written as 4x ds_write_b64 (was 16 scalar b16).

#define QBLK   64
#define KVBLK  64
#define DHEAD  128
#define SEQ    2048
#define KPAD   136   // 128+8 f16 -> row stride 272 B
#define PPAD   72    // 64+8

typedef _Float16 f16x8 __attribute__((ext_vector_type(8)));
typedef _Float16 f16x4 __attribute__((ext_vector_type(4)));
typedef float    f32x4 __attribute__((ext_vector_type(4)));

__global__ __launch_bounds__(256, 3)
void attn_fwd_kernel(const float* __restrict__ Q, const float* __restrict__ K,
                     const float* __restrict__ V, float* __restrict__ O) {
    __shared__ __align__(16) _Float16 K_lds[KVBLK * KPAD];
    __shared__ __align__(16) _Float16 V_lds[KVBLK * DHEAD];   // subtiled [kv/4][d/16][4][16]
    __shared__ __align__(16) _Float16 P_lds[4 * 16 * PPAD];

    const int tid  = threadIdx.x;
    const int lane = tid & 63;
    const int wave = tid >> 6;
    const int g    = lane >> 4;   // lane-group 0..3
    const int lg   = lane & 15;

    // ---- XCD-gather swizzle: each XCD gets 8 whole heads (all their q-tiles).
    const int flat    = blockIdx.x + gridDim.x * blockIdx.y;   // 0..2047
    const int newflat = (flat & 7) * 256 + (flat >> 3);        // bijective (2048 = 8*256)
    const int qtile   = newflat & 31;
    const int bh      = newflat >> 5;

    const size_t base = (size_t)bh * SEQ * DHEAD;
    const float* Qg = Q + base + (size_t)(qtile * QBLK) * DHEAD;
    const float* Kg = K + base;
    const float* Vg = V + base;
    float*       Og = O + base + (size_t)(qtile * QBLK) * DHEAD;

    // per-lane base byte-address for ds_read_b64_tr_b16 on V_lds:
    //   window (128B subtile) = kt*8192 + g*2048 + s*1024 + dt*128  (via offset:)
    //   column within window  = lg  -> lane-offset lg*8 bytes
    const unsigned trbase = (unsigned)(size_t)&V_lds[0] + (unsigned)(g * 2048 + lg * 8);

    // ---- Q fragments in registers (fp16). Frag layout: idx=lane&15, k=(lane>>4)*8+i
    //      (identical for A and B operands -> usable directly as B in mfma(K,Q))
    f16x8 qf[4];
    {
        const float* qrow = Qg + (size_t)(wave * 16 + lg) * DHEAD;
        #pragma unroll
        for (int dc = 0; dc < 4; ++dc) {
            const int d0 = dc * 32 + g * 8;
            float4 f0 = *(const float4*)(qrow + d0);
            float4 f1 = *(const float4*)(qrow + d0 + 4);
            qf[dc][0] = (_Float16)f0.x; qf[dc][1] = (_Float16)f0.y;
            qf[dc][2] = (_Float16)f0.z; qf[dc][3] = (_Float16)f0.w;
            qf[dc][4] = (_Float16)f1.x; qf[dc][5] = (_Float16)f1.y;
            qf[dc][6] = (_Float16)f1.z; qf[dc][7] = (_Float16)f1.w;
        }
    }

    // ---- online-softmax state (per-lane scalar: this lane's q-row is lg) + acc
    f32x4 acc[8];
    #pragma unroll
    for (int dt = 0; dt < 8; ++dt) { acc[dt][0]=0.f; acc[dt][1]=0.f; acc[dt][2]=0.f; acc[dt][3]=0.f; }
    float m = -1e30f, l = 0.f;

    for (int t = 0; t < SEQ / KVBLK; ++t) {
        // ---- stage K tile (row-major fp16, padded; <=2-way banks)
        {
            const float* Kt = Kg + (size_t)t * KVBLK * DHEAD;
            #pragma unroll
            for (int j = 0; j < 4; ++j) {
                const int c   = tid + 256 * j;      // 0..1023
                const int row = c >> 4;
                const int dc  = (c & 15) * 8;
                float4 f0 = *(const float4*)(Kt + row * DHEAD + dc);
                float4 f1 = *(const float4*)(Kt + row * DHEAD + dc + 4);
                f16x8 vh;
                vh[0]=(_Float16)f0.x; vh[1]=(_Float16)f0.y; vh[2]=(_Float16)f0.z; vh[3]=(_Float16)f0.w;
                vh[4]=(_Float16)f1.x; vh[5]=(_Float16)f1.y; vh[6]=(_Float16)f1.z; vh[7]=(_Float16)f1.w;
                *(f16x8*)&K_lds[row * KPAD + dc] = vh;
            }
            // ---- stage V tile into subtiled layout [kv/4][d/16][4][16]
            const float* Vt = Vg + (size_t)t * KVBLK * DHEAD;
            #pragma unroll
            for (int j = 0; j < 4; ++j) {
                const int c   = tid + 256 * j;                 // 0..1023
                const int d8  = (c & 1) | (((c >> 3) & 7) << 1);   // 0..15
                const int row = ((c >> 1) & 3) | ((c >> 6) << 2);  // 0..63
                const int d0  = d8 * 8;
                float4 f0 = *(const float4*)(Vt + row * DHEAD + d0);
                float4 f1 = *(const float4*)(Vt + row * DHEAD + d0 + 4);
                f16x8 vv;
                vv[0]=(_Float16)f0.x; vv[1]=(_Float16)f0.y; vv[2]=(_Float16)f0.z; vv[3]=(_Float16)f0.w;
                vv[4]=(_Float16)f1.x; vv[5]=(_Float16)f1.y; vv[6]=(_Float16)f1.z; vv[7]=(_Float16)f1.w;
                const int st = (row >> 2) * 8 + (d0 >> 4);
                *(f16x8*)&V_lds[st * 64 + (row & 3) * 16 + (d0 & 15)] = vv;
            }
        }
        __syncthreads();

        // ---- S^T = K * Q^T via mfma(K_frag, Q_frag):
        //      lane holds S[kv = ct*16 + g*4 + r][q-row = lg]
        f32x4 s[4];
        __builtin_amdgcn_s_setprio(1);
        #pragma unroll
        for (int ct = 0; ct < 4; ++ct) {
            f32x4 a; a[0]=0.f; a[1]=0.f; a[2]=0.f; a[3]=0.f;
            #pragma unroll
            for (int dc = 0; dc < 4; ++dc) {
                const int off = (ct * 16 + lg) * KPAD + dc * 32 + g * 8;
                f16x8 kh = *(const f16x8*)&K_lds[off];
                a = __builtin_amdgcn_mfma_f32_16x16x32_f16(kh, qf[dc], a, 0, 0, 0);
            }
            s[ct] = a;
        }
        __builtin_amdgcn_s_setprio(0);

        // ---- online softmax: lane owns q-row lg; 16 in-reg values + 2 shfl reduce
        float pmax = s[0][0];
        #pragma unroll
        for (int ct = 0; ct < 4; ++ct)
            #pragma unroll
            for (int r = 0; r < 4; ++r)
                pmax = fmaxf(pmax, s[ct][r]);
        pmax = fmaxf(pmax, __shfl_xor(pmax, 16));
        pmax = fmaxf(pmax, __shfl_xor(pmax, 32));
        const float mnew = fmaxf(m, pmax);
        const float sc   = __expf(m - mnew);
        m = mnew;
        float rs = 0.f;
        #pragma unroll
        for (int ct = 0; ct < 4; ++ct)
            #pragma unroll
            for (int r = 0; r < 4; ++r) {
                float p = __expf(s[ct][r] - mnew);
                s[ct][r] = p;
                rs += p;
            }
        rs += __shfl_xor(rs, 16);
        rs += __shfl_xor(rs, 32);
        l = l * sc + rs;

        // ---- rescale acc: acc rows are q = g*4+r; fetch sc of that row
        //      (row q's sc lives at lanes with lg==q; pick the one in group g)
        #pragma unroll
        for (int r = 0; r < 4; ++r) {
            const float scr = __shfl(sc, g * 20 + r);   // lane g*16 + (g*4+r)
            #pragma unroll
            for (int dt = 0; dt < 8; ++dt) acc[dt][r] *= scr;
        }

        // ---- P -> LDS: lane's 16 values are row lg, kv = ct*16+g*4+r -> 4x b64
        _Float16* pbase = &P_lds[wave * 16 * PPAD];
        #pragma unroll
        for (int ct = 0; ct < 4; ++ct) {
            f16x4 pk;
            pk[0] = (_Float16)s[ct][0]; pk[1] = (_Float16)s[ct][1];
            pk[2] = (_Float16)s[ct][2]; pk[3] = (_Float16)s[ct][3];
            *(f16x4*)&pbase[lg * PPAD + ct * 16 + g * 4] = pk;
        }

        // ---- O += P * V  (P as A-frag: row=lg, k=kt*32+g*8+i; V via tr_read)
        #pragma unroll
        for (int kt = 0; kt < 2; ++kt) {
            f16x8 pf = *(const f16x8*)&pbase[lg * PPAD + kt * 32 + g * 8];
            #pragma unroll
            for (int dp = 0; dp < 4; ++dp) {
                f16x4 a0, a1, b0, b1;
                asm volatile(
                    "ds_read_b64_tr_b16 %0, %4 offset:%5\n\t"
                    "ds_read_b64_tr_b16 %1, %4 offset:%6\n\t"
                    "ds_read_b64_tr_b16 %2, %4 offset:%7\n\t"
                    "ds_read_b64_tr_b16 %3, %4 offset:%8\n\t"
                    "s_waitcnt lgkmcnt(0)"
                    : "=&v"(a0), "=&v"(a1), "=&v"(b0), "=&v"(b1)
                    : "v"(trbase),
                      "i"(kt * 8192 + (dp * 2 + 0) * 128),
                      "i"(kt * 8192 + 1024 + (dp * 2 + 0) * 128),
                      "i"(kt * 8192 + (dp * 2 + 1) * 128),
                      "i"(kt * 8192 + 1024 + (dp * 2 + 1) * 128)
                    : "memory");
                __builtin_amdgcn_sched_barrier(0);
                f16x8 vf0 = __builtin_shufflevector(a0, a1, 0, 1, 2, 3, 4, 5, 6, 7);
                f16x8 vf1 = __builtin_shufflevector(b0, b1, 0, 1, 2, 3, 4, 5, 6, 7);
                __builtin_amdgcn_s_setprio(1);
                acc[dp * 2 + 0] = __builtin_amdgcn_mfma_f32_16x16x32_f16(pf, vf0, acc[dp * 2 + 0], 0, 0, 0);
                acc[dp * 2 + 1] = __builtin_amdgcn_mfma_f32_16x16x32_f16(pf, vf1, acc[dp * 2 + 1], 0, 0, 0);
                __builtin_amdgcn_s_setprio(0);
            }
        }
        __syncthreads();
    }

    // ---- epilogue: O / l  (l of row g*4+r fetched by shfl, as with sc)
    const float linv = 1.f / l;
    float inv[4];
    #pragma unroll
    for (int r = 0; r < 4; ++r) inv[r] = __shfl(linv, g * 20 + r);
    float* ob = Og + (size_t)(wave * 16) * DHEAD;
    #pragma unroll
    for (int dt = 0; dt < 8; ++dt)
        #pragma unroll
        for (int r = 0; r < 4; ++r)
            ob[(size_t)(g * 4 + r) * DHEAD + dt * 16 + lg] = acc[dt][r] * inv[r];
}

extern "C" void kernel_launch(void* const* d_in, const int* in_sizes, int n_in,
                              void* d_out, int out_size, void* d_ws, size_t ws_size,
                              hipStream_t stream) {
    const float* q = (const float*)d_in[0];
    const float* k = (const float*)d_in[1];
    const float* v = (const float*)d_in[2];
    float* out = (float*)d_out;
    const int BH = in_sizes[0] / (SEQ * DHEAD);   // 64
    dim3 grid(SEQ / QBLK, BH);
    attn_fwd_kernel<<<grid, dim3(256), 0, stream>>>(q, k, v, out);
}

// Round 11
// 259.368 us; speedup vs baseline: 1.7603x; 1.0932x over previous
//
#include <hip/hip_runtime.h>
#include <hip/hip_bf16.h>

// Flash-attention forward, B=4 H=16 S=2048 D=128, fp32 in/out, no 1/sqrt(D) scale.
// Round 10: fp16 pre-pass into d_ws (K XOR-swizzled linear, V subtiled), main kernel
//   stages via global_load_lds (no cvt, no VGPR round-trip). P -> stride 64 + XOR
//   swizzle. LDS = 16384+16384+8192 = 40960 B exactly -> 4 blocks/CU.
//   Keeps R9's swapped-operand QK^T softmax, XCD-gather, tr_read V, setprio.
//   Fallback to R9 kernel if ws_size < 64 MB.

#define QBLK   64
#define KVBLK  64
#define DHEAD  128
#define SEQ    2048
#define KPAD   136   // legacy kernel only
#define PPAD   72    // legacy kernel only

typedef _Float16 f16x8 __attribute__((ext_vector_type(8)));
typedef _Float16 f16x4 __attribute__((ext_vector_type(4)));
typedef float    f32x4 __attribute__((ext_vector_type(4)));

#define AS1P(x) ((const __attribute__((address_space(1))) void*)(size_t)(x))
#define AS3P(x) ((__attribute__((address_space(3))) void*)(unsigned long long)(unsigned)(size_t)(x))

// ---------------- pre-pass: fp32 -> fp16, LDS-linear tile layouts ----------------
__global__ __launch_bounds__(256)
void preconv_kernel(const float* __restrict__ K, const float* __restrict__ V,
                    _Float16* __restrict__ Kp, _Float16* __restrict__ Vp) {
    const int bt = blockIdx.x;                       // bh*32 + t (tiles contiguous)
    const size_t src = (size_t)bt * (KVBLK * DHEAD);
    const float* Kt = K + src;
    const float* Vt = V + src;
    _Float16* Ko = Kp + src;
    _Float16* Vo = Vp + src;
    #pragma unroll
    for (int j = 0; j < 4; ++j) {
        const int c = threadIdx.x + 256 * j;         // 0..1023
        // K: row-major, XOR-swizzled at 8-element granule
        {
            const int row = c >> 4;
            const int d0  = (c & 15) * 8;
            float4 f0 = *(const float4*)(Kt + row * DHEAD + d0);
            float4 f1 = *(const float4*)(Kt + row * DHEAD + d0 + 4);
            f16x8 h;
            h[0]=(_Float16)f0.x; h[1]=(_Float16)f0.y; h[2]=(_Float16)f0.z; h[3]=(_Float16)f0.w;
            h[4]=(_Float16)f1.x; h[5]=(_Float16)f1.y; h[6]=(_Float16)f1.z; h[7]=(_Float16)f1.w;
            *(f16x8*)&Ko[row * 128 + (d0 ^ ((row & 7) << 3))] = h;
        }
        // V: subtiled [kv/4][d/16][4][16] (element order identical to R9's V_lds)
        {
            const int d8  = (c & 1) | (((c >> 3) & 7) << 1);   // 0..15
            const int row = ((c >> 1) & 3) | ((c >> 6) << 2);  // 0..63
            const int d0  = d8 * 8;
            float4 f0 = *(const float4*)(Vt + row * DHEAD + d0);
            float4 f1 = *(const float4*)(Vt + row * DHEAD + d0 + 4);
            f16x8 h;
            h[0]=(_Float16)f0.x; h[1]=(_Float16)f0.y; h[2]=(_Float16)f0.z; h[3]=(_Float16)f0.w;
            h[4]=(_Float16)f1.x; h[5]=(_Float16)f1.y; h[6]=(_Float16)f1.z; h[7]=(_Float16)f1.w;
            const int st = (row >> 2) * 8 + (d0 >> 4);
            *(f16x8*)&Vo[st * 64 + (row & 3) * 16 + (d0 & 15)] = h;
        }
    }
}

// ---------------- main kernel: gload_lds staging ----------------
__global__ __launch_bounds__(256, 3)
void attn_fwd_kernel(const float* __restrict__ Q, const _Float16* __restrict__ Kp,
                     const _Float16* __restrict__ Vp, float* __restrict__ O) {
    __shared__ __align__(16) _Float16 K_lds[KVBLK * DHEAD];   // linear + XOR swizzle
    __shared__ __align__(16) _Float16 V_lds[KVBLK * DHEAD];   // subtiled [kv/4][d/16][4][16]
    __shared__ __align__(16) _Float16 P_lds[4 * 16 * 64];     // stride 64 + XOR swizzle

    const int tid  = threadIdx.x;
    const int lane = tid & 63;
    const int wave = tid >> 6;
    const int g    = lane >> 4;
    const int lg   = lane & 15;

    // XCD-gather swizzle
    const int flat    = blockIdx.x + gridDim.x * blockIdx.y;
    const int newflat = (flat & 7) * 256 + (flat >> 3);
    const int qtile   = newflat & 31;
    const int bh      = newflat >> 5;

    const float* Qg = Q + (size_t)bh * SEQ * DHEAD + (size_t)(qtile * QBLK) * DHEAD;
    float*       Og = O + (size_t)bh * SEQ * DHEAD + (size_t)(qtile * QBLK) * DHEAD;

    // tr_read base: window = kt*8192 + g*2048 + s*1024 + dt*128 ; column = lg (lg*8 B)
    const unsigned trbase = (unsigned)(size_t)&V_lds[0] + (unsigned)(g * 2048 + lg * 8);

    // ---- Q fragments (fp16). Frag layout: idx=lane&15, k=(lane>>4)*8+i
    f16x8 qf[4];
    {
        const float* qrow = Qg + (size_t)(wave * 16 + lg) * DHEAD;
        #pragma unroll
        for (int dc = 0; dc < 4; ++dc) {
            const int d0 = dc * 32 + g * 8;
            float4 f0 = *(const float4*)(qrow + d0);
            float4 f1 = *(const float4*)(qrow + d0 + 4);
            qf[dc][0] = (_Float16)f0.x; qf[dc][1] = (_Float16)f0.y;
            qf[dc][2] = (_Float16)f0.z; qf[dc][3] = (_Float16)f0.w;
            qf[dc][4] = (_Float16)f1.x; qf[dc][5] = (_Float16)f1.y;
            qf[dc][6] = (_Float16)f1.z; qf[dc][7] = (_Float16)f1.w;
        }
    }

    f32x4 acc[8];
    #pragma unroll
    for (int dt = 0; dt < 8; ++dt) { acc[dt][0]=0.f; acc[dt][1]=0.f; acc[dt][2]=0.f; acc[dt][3]=0.f; }
    float m = -1e30f, l = 0.f;

    for (int t = 0; t < SEQ / KVBLK; ++t) {
        // ---- stage K+V: 8 global_load_lds dwordx4 per wave (1KB each), zero VALU
        {
            const _Float16* Ktile = Kp + (size_t)(bh * 32 + t) * (KVBLK * DHEAD);
            const _Float16* Vtile = Vp + (size_t)(bh * 32 + t) * (KVBLK * DHEAD);
            #pragma unroll
            for (int i = 0; i < 4; ++i) {
                const int eoff = wave * 2048 + i * 512;          // elements (1KB per call)
                __builtin_amdgcn_global_load_lds(AS1P(Ktile + eoff + lane * 8),
                                                 AS3P(&K_lds[eoff]), 16, 0, 0);
                __builtin_amdgcn_global_load_lds(AS1P(Vtile + eoff + lane * 8),
                                                 AS3P(&V_lds[eoff]), 16, 0, 0);
            }
        }
        __syncthreads();   // compiler drains vmcnt before s_barrier

        // ---- S^T = mfma(K, Q): lane holds S[kv=ct*16+g*4+r][q-row=lg]
        f32x4 s[4];
        __builtin_amdgcn_s_setprio(1);
        #pragma unroll
        for (int ct = 0; ct < 4; ++ct) {
            f32x4 a; a[0]=0.f; a[1]=0.f; a[2]=0.f; a[3]=0.f;
            #pragma unroll
            for (int dc = 0; dc < 4; ++dc) {
                const int krow = ct * 16 + lg;
                const int off  = krow * 128 + ((dc * 32 + g * 8) ^ ((krow & 7) << 3));
                f16x8 kh = *(const f16x8*)&K_lds[off];
                a = __builtin_amdgcn_mfma_f32_16x16x32_f16(kh, qf[dc], a, 0, 0, 0);
            }
            s[ct] = a;
        }
        __builtin_amdgcn_s_setprio(0);

        // ---- online softmax: lane owns q-row lg; 15 VALU + 2 shfl
        float pmax = s[0][0];
        #pragma unroll
        for (int ct = 0; ct < 4; ++ct)
            #pragma unroll
            for (int r = 0; r < 4; ++r)
                pmax = fmaxf(pmax, s[ct][r]);
        pmax = fmaxf(pmax, __shfl_xor(pmax, 16));
        pmax = fmaxf(pmax, __shfl_xor(pmax, 32));
        const float mnew = fmaxf(m, pmax);
        const float sc   = __expf(m - mnew);
        m = mnew;
        float rs = 0.f;
        #pragma unroll
        for (int ct = 0; ct < 4; ++ct)
            #pragma unroll
            for (int r = 0; r < 4; ++r) {
                float p = __expf(s[ct][r] - mnew);
                s[ct][r] = p;
                rs += p;
            }
        rs += __shfl_xor(rs, 16);
        rs += __shfl_xor(rs, 32);
        l = l * sc + rs;

        // ---- rescale acc (row q=g*4+r; its sc lives at lane g*16 + q)
        #pragma unroll
        for (int r = 0; r < 4; ++r) {
            const float scr = __shfl(sc, g * 20 + r);
            #pragma unroll
            for (int dt = 0; dt < 8; ++dt) acc[dt][r] *= scr;
        }

        // ---- P -> LDS, stride 64 + XOR ^((lg&7)<<3): b64 writes 2-way (free)
        _Float16* pbase = &P_lds[wave * 16 * 64];
        #pragma unroll
        for (int ct = 0; ct < 4; ++ct) {
            f16x4 pk;
            pk[0] = (_Float16)s[ct][0]; pk[1] = (_Float16)s[ct][1];
            pk[2] = (_Float16)s[ct][2]; pk[3] = (_Float16)s[ct][3];
            *(f16x4*)&pbase[lg * 64 + ((ct * 16 + g * 4) ^ ((lg & 7) << 3))] = pk;
        }

        // ---- O += P * V  (P A-frag with same XOR; V via tr_read)
        #pragma unroll
        for (int kt = 0; kt < 2; ++kt) {
            f16x8 pf = *(const f16x8*)&pbase[lg * 64 + ((kt * 32 + g * 8) ^ ((lg & 7) << 3))];
            #pragma unroll
            for (int dp = 0; dp < 4; ++dp) {
                f16x4 a0, a1, b0, b1;
                asm volatile(
                    "ds_read_b64_tr_b16 %0, %4 offset:%5\n\t"
                    "ds_read_b64_tr_b16 %1, %4 offset:%6\n\t"
                    "ds_read_b64_tr_b16 %2, %4 offset:%7\n\t"
                    "ds_read_b64_tr_b16 %3, %4 offset:%8\n\t"
                    "s_waitcnt lgkmcnt(0)"
                    : "=&v"(a0), "=&v"(a1), "=&v"(b0), "=&v"(b1)
                    : "v"(trbase),
                      "i"(kt * 8192 + (dp * 2 + 0) * 128),
                      "i"(kt * 8192 + 1024 + (dp * 2 + 0) * 128),
                      "i"(kt * 8192 + (dp * 2 + 1) * 128),
                      "i"(kt * 8192 + 1024 + (dp * 2 + 1) * 128)
                    : "memory");
                __builtin_amdgcn_sched_barrier(0);
                f16x8 vf0 = __builtin_shufflevector(a0, a1, 0, 1, 2, 3, 4, 5, 6, 7);
                f16x8 vf1 = __builtin_shufflevector(b0, b1, 0, 1, 2, 3, 4, 5, 6, 7);
                __builtin_amdgcn_s_setprio(1);
                acc[dp * 2 + 0] = __builtin_amdgcn_mfma_f32_16x16x32_f16(pf, vf0, acc[dp * 2 + 0], 0, 0, 0);
                acc[dp * 2 + 1] = __builtin_amdgcn_mfma_f32_16x16x32_f16(pf, vf1, acc[dp * 2 + 1], 0, 0, 0);
                __builtin_amdgcn_s_setprio(0);
            }
        }
        __syncthreads();
    }

    // ---- epilogue
    const float linv = 1.f / l;
    float inv[4];
    #pragma unroll
    for (int r = 0; r < 4; ++r) inv[r] = __shfl(linv, g * 20 + r);
    float* ob = Og + (size_t)(wave * 16) * DHEAD;
    #pragma unroll
    for (int dt = 0; dt < 8; ++dt)
        #pragma unroll
        for (int r = 0; r < 4; ++r)
            ob[(size_t)(g * 4 + r) * DHEAD + dt * 16 + lg] = acc[dt][r] * inv[r];
}

// ---------------- legacy (R9) kernel: fallback when ws too small ----------------
__global__ __launch_bounds__(256, 3)
void attn_fwd_legacy(const float* __restrict__ Q, const float* __restrict__ K,
                     const float* __restrict__ V, float* __restrict__ O) {
    __shared__ __align__(16) _Float16 K_lds[KVBLK * KPAD];
    __shared__ __align__(16) _Float16 V_lds[KVBLK * DHEAD];
    __shared__ __align__(16) _Float16 P_lds[4 * 16 * PPAD];

    const int tid  = threadIdx.x;
    const int lane = tid & 63;
    const int wave = tid >> 6;
    const int g    = lane >> 4;
    const int lg   = lane & 15;

    const int flat    = blockIdx.x + gridDim.x * blockIdx.y;
    const int newflat = (flat & 7) * 256 + (flat >> 3);
    const int qtile   = newflat & 31;
    const int bh      = newflat >> 5;

    const size_t base = (size_t)bh * SEQ * DHEAD;
    const float* Qg = Q + base + (size_t)(qtile * QBLK) * DHEAD;
    const float* Kg = K + base;
    const float* Vg = V + base;
    float*       Og = O + base + (size_t)(qtile * QBLK) * DHEAD;

    const unsigned trbase = (unsigned)(size_t)&V_lds[0] + (unsigned)(g * 2048 + lg * 8);

    f16x8 qf[4];
    {
        const float* qrow = Qg + (size_t)(wave * 16 + lg) * DHEAD;
        #pragma unroll
        for (int dc = 0; dc < 4; ++dc) {
            const int d0 = dc * 32 + g * 8;
            float4 f0 = *(const float4*)(qrow + d0);
            float4 f1 = *(const float4*)(qrow + d0 + 4);
            qf[dc][0] = (_Float16)f0.x; qf[dc][1] = (_Float16)f0.y;
            qf[dc][2] = (_Float16)f0.z; qf[dc][3] = (_Float16)f0.w;
            qf[dc][4] = (_Float16)f1.x; qf[dc][5] = (_Float16)f1.y;
            qf[dc][6] = (_Float16)f1.z; qf[dc][7] = (_Float16)f1.w;
        }
    }

    f32x4 acc[8];
    #pragma unroll
    for (int dt = 0; dt < 8; ++dt) { acc[dt][0]=0.f; acc[dt][1]=0.f; acc[dt][2]=0.f; acc[dt][3]=0.f; }
    float m = -1e30f, l = 0.f;

    for (int t = 0; t < SEQ / KVBLK; ++t) {
        {
            const float* Kt = Kg + (size_t)t * KVBLK * DHEAD;
            #pragma unroll
            for (int j = 0; j < 4; ++j) {
                const int c   = tid + 256 * j;
                const int row = c >> 4;
                const int dc  = (c & 15) * 8;
                float4 f0 = *(const float4*)(Kt + row * DHEAD + dc);
                float4 f1 = *(const float4*)(Kt + row * DHEAD + dc + 4);
                f16x8 vh;
                vh[0]=(_Float16)f0.x; vh[1]=(_Float16)f0.y; vh[2]=(_Float16)f0.z; vh[3]=(_Float16)f0.w;
                vh[4]=(_Float16)f1.x; vh[5]=(_Float16)f1.y; vh[6]=(_Float16)f1.z; vh[7]=(_Float16)f1.w;
                *(f16x8*)&K_lds[row * KPAD + dc] = vh;
            }
            const float* Vt = Vg + (size_t)t * KVBLK * DHEAD;
            #pragma unroll
            for (int j = 0; j < 4; ++j) {
                const int c   = tid + 256 * j;
                const int d8  = (c & 1) | (((c >> 3) & 7) << 1);
                const int row = ((c >> 1) & 3) | ((c >> 6) << 2);
                const int d0  = d8 * 8;
                float4 f0 = *(const float4*)(Vt + row * DHEAD + d0);
                float4 f1 = *(const float4*)(Vt + row * DHEAD + d0 + 4);
                f16x8 vv;
                vv[0]=(_Float16)f0.x; vv[1]=(_Float16)f0.y; vv[2]=(_Float16)f0.z; vv[3]=(_Float16)f0.w;
                vv[4]=(_Float16)f1.x; vv[5]=(_Float16)f1.y; vv[6]=(_Float16)f1.z; vv[7]=(_Float16)f1.w;
                const int st = (row >> 2) * 8 + (d0 >> 4);
                *(f16x8*)&V_lds[st * 64 + (row & 3) * 16 + (d0 & 15)] = vv;
            }
        }
        __syncthreads();

        f32x4 s[4];
        __builtin_amdgcn_s_setprio(1);
        #pragma unroll
        for (int ct = 0; ct < 4; ++ct) {
            f32x4 a; a[0]=0.f; a[1]=0.f; a[2]=0.f; a[3]=0.f;
            #pragma unroll
            for (int dc = 0; dc < 4; ++dc) {
                const int off = (ct * 16 + lg) * KPAD + dc * 32 + g * 8;
                f16x8 kh = *(const f16x8*)&K_lds[off];
                a = __builtin_amdgcn_mfma_f32_16x16x32_f16(kh, qf[dc], a, 0, 0, 0);
            }
            s[ct] = a;
        }
        __builtin_amdgcn_s_setprio(0);

        float pmax = s[0][0];
        #pragma unroll
        for (int ct = 0; ct < 4; ++ct)
            #pragma unroll
            for (int r = 0; r < 4; ++r)
                pmax = fmaxf(pmax, s[ct][r]);
        pmax = fmaxf(pmax, __shfl_xor(pmax, 16));
        pmax = fmaxf(pmax, __shfl_xor(pmax, 32));
        const float mnew = fmaxf(m, pmax);
        const float sc   = __expf(m - mnew);
        m = mnew;
        float rs = 0.f;
        #pragma unroll
        for (int ct = 0; ct < 4; ++ct)
            #pragma unroll
            for (int r = 0; r < 4; ++r) {
                float p = __expf(s[ct][r] - mnew);
                s[ct][r] = p;
                rs += p;
            }
        rs += __shfl_xor(rs, 16);
        rs += __shfl_xor(rs, 32);
        l = l * sc + rs;

        #pragma unroll
        for (int r = 0; r < 4; ++r) {
            const float scr = __shfl(sc, g * 20 + r);
            #pragma unroll
            for (int dt = 0; dt < 8; ++dt) acc[dt][r] *= scr;
        }

        _Float16* pbase = &P_lds[wave * 16 * PPAD];
        #pragma unroll
        for (int ct = 0; ct < 4; ++ct) {
            f16x4 pk;
            pk[0] = (_Float16)s[ct][0]; pk[1] = (_Float16)s[ct][1];
            pk[2] = (_Float16)s[ct][2]; pk[3] = (_Float16)s[ct][3];
            *(f16x4*)&pbase[lg * PPAD + ct * 16 + g * 4] = pk;
        }

        #pragma unroll
        for (int kt = 0; kt < 2; ++kt) {
            f16x8 pf = *(const f16x8*)&pbase[lg * PPAD + kt * 32 + g * 8];
            #pragma unroll
            for (int dp = 0; dp < 4; ++dp) {
                f16x4 a0, a1, b0, b1;
                asm volatile(
                    "ds_read_b64_tr_b16 %0, %4 offset:%5\n\t"
                    "ds_read_b64_tr_b16 %1, %4 offset:%6\n\t"
                    "ds_read_b64_tr_b16 %2, %4 offset:%7\n\t"
                    "ds_read_b64_tr_b16 %3, %4 offset:%8\n\t"
                    "s_waitcnt lgkmcnt(0)"
                    : "=&v"(a0), "=&v"(a1), "=&v"(b0), "=&v"(b1)
                    : "v"(trbase),
                      "i"(kt * 8192 + (dp * 2 + 0) * 128),
                      "i"(kt * 8192 + 1024 + (dp * 2 + 0) * 128),
                      "i"(kt * 8192 + (dp * 2 + 1) * 128),
                      "i"(kt * 8192 + 1024 + (dp * 2 + 1) * 128)
                    : "memory");
                __builtin_amdgcn_sched_barrier(0);
                f16x8 vf0 = __builtin_shufflevector(a0, a1, 0, 1, 2, 3, 4, 5, 6, 7);
                f16x8 vf1 = __builtin_shufflevector(b0, b1, 0, 1, 2, 3, 4, 5, 6, 7);
                __builtin_amdgcn_s_setprio(1);
                acc[dp * 2 + 0] = __builtin_amdgcn_mfma_f32_16x16x32_f16(pf, vf0, acc[dp * 2 + 0], 0, 0, 0);
                acc[dp * 2 + 1] = __builtin_amdgcn_mfma_f32_16x16x32_f16(pf, vf1, acc[dp * 2 + 1], 0, 0, 0);
                __builtin_amdgcn_s_setprio(0);
            }
        }
        __syncthreads();
    }

    const float linv = 1.f / l;
    float inv[4];
    #pragma unroll
    for (int r = 0; r < 4; ++r) inv[r] = __shfl(linv, g * 20 + r);
    float* ob = Og + (size_t)(wave * 16) * DHEAD;
    #pragma unroll
    for (int dt = 0; dt < 8; ++dt)
        #pragma unroll
        for (int r = 0; r < 4; ++r)
            ob[(size_t)(g * 4 + r) * DHEAD + dt * 16 + lg] = acc[dt][r] * inv[r];
}

extern "C" void kernel_launch(void* const* d_in, const int* in_sizes, int n_in,
                              void* d_out, int out_size, void* d_ws, size_t ws_size,
                              hipStream_t stream) {
    const float* q = (const float*)d_in[0];
    const float* k = (const float*)d_in[1];
    const float* v = (const float*)d_in[2];
    float* out = (float*)d_out;
    const int BH = in_sizes[0] / (SEQ * DHEAD);   // 64
    dim3 grid(SEQ / QBLK, BH);

    const size_t elems = (size_t)BH * SEQ * DHEAD;           // 16M
    const size_t need  = elems * 2 * sizeof(_Float16);       // 64 MB
    if (ws_size >= need) {
        _Float16* Kp = (_Float16*)d_ws;
        _Float16* Vp = Kp + elems;
        preconv_kernel<<<dim3(BH * (SEQ / KVBLK)), dim3(256), 0, stream>>>(k, v, Kp, Vp);
        attn_fwd_kernel<<<grid, dim3(256), 0, stream>>>(q, Kp, Vp, out);
    } else {
        attn_fwd_legacy<<<grid, dim3(256), 0, stream>>>(q, k, v, out);
    }
}

// Round 12
// 250.791 us; speedup vs baseline: 1.8205x; 1.0342x over previous
//
#include <hip/hip_runtime.h>
#include <hip/hip_bf16.h>

// Flash-attention forward, B=4 H=16 S=2048 D=128, fp32 in/out, no 1/sqrt(D) scale.
// Round 11: eliminate tr_read 4-way conflicts — pre-pass now stores V TRANSPOSED
//   (V^T [d][kv], XOR-swizzled like K), so PV B-frags are plain ds_read_b128
//   (bank-identical to the K path). No asm, no per-dp lgkmcnt(0) fences.
//   Keeps: swapped-operand QK^T softmax, XCD-gather, global_load_lds staging,
//   setprio, P stride-64 XOR. LDS = 40960 B -> 4 blocks/CU.

#define QBLK   64
#define KVBLK  64
#define DHEAD  128
#define SEQ    2048
#define KPAD   136   // legacy kernel only
#define PPAD   72    // legacy kernel only

typedef _Float16 f16x8 __attribute__((ext_vector_type(8)));
typedef _Float16 f16x4 __attribute__((ext_vector_type(4)));
typedef float    f32x4 __attribute__((ext_vector_type(4)));

#define AS1P(x) ((const __attribute__((address_space(1))) void*)(size_t)(x))
#define AS3P(x) ((__attribute__((address_space(3))) void*)(unsigned long long)(unsigned)(size_t)(x))

// ---------------- pre-pass: fp32 -> fp16, LDS-linear tile layouts ----------------
__global__ __launch_bounds__(256)
void preconv_kernel(const float* __restrict__ K, const float* __restrict__ V,
                    _Float16* __restrict__ Kp, _Float16* __restrict__ Vp) {
    const int bt = blockIdx.x;                       // bh*32 + t (tiles contiguous)
    const size_t src = (size_t)bt * (KVBLK * DHEAD);
    const float* Kt = K + src;
    const float* Vt = V + src;
    _Float16* Ko = Kp + src;
    _Float16* Vo = Vp + src;
    #pragma unroll
    for (int j = 0; j < 4; ++j) {
        const int c = threadIdx.x + 256 * j;         // 0..1023
        // K: row-major [kv][d], XOR-swizzled at 8-element granule
        {
            const int row = c >> 4;
            const int d0  = (c & 15) * 8;
            float4 f0 = *(const float4*)(Kt + row * DHEAD + d0);
            float4 f1 = *(const float4*)(Kt + row * DHEAD + d0 + 4);
            f16x8 h;
            h[0]=(_Float16)f0.x; h[1]=(_Float16)f0.y; h[2]=(_Float16)f0.z; h[3]=(_Float16)f0.w;
            h[4]=(_Float16)f1.x; h[5]=(_Float16)f1.y; h[6]=(_Float16)f1.z; h[7]=(_Float16)f1.w;
            *(f16x8*)&Ko[row * 128 + (d0 ^ ((row & 7) << 3))] = h;
        }
        // V^T: [d][kv], kv-granule XOR-swizzled by d-row (read path == K path)
        {
            const int d   = c & 127;                 // coalesced across lanes per i
            const int kvg = c >> 7;                  // 0..7
            f16x8 h;
            #pragma unroll
            for (int i = 0; i < 8; ++i)
                h[i] = (_Float16)Vt[(kvg * 8 + i) * DHEAD + d];
            *(f16x8*)&Vo[d * 64 + ((kvg * 8) ^ ((d & 7) << 3))] = h;
        }
    }
}

// ---------------- main kernel: gload_lds staging, all-b128 LDS reads ----------------
__global__ __launch_bounds__(256, 3)
void attn_fwd_kernel(const float* __restrict__ Q, const _Float16* __restrict__ Kp,
                     const _Float16* __restrict__ Vp, float* __restrict__ O) {
    __shared__ __align__(16) _Float16 K_lds[KVBLK * DHEAD];   // [kv][d] + XOR swizzle
    __shared__ __align__(16) _Float16 V_lds[DHEAD * KVBLK];   // [d][kv] + XOR swizzle
    __shared__ __align__(16) _Float16 P_lds[4 * 16 * 64];     // stride 64 + XOR swizzle

    const int tid  = threadIdx.x;
    const int lane = tid & 63;
    const int wave = tid >> 6;
    const int g    = lane >> 4;
    const int lg   = lane & 15;

    // XCD-gather swizzle
    const int flat    = blockIdx.x + gridDim.x * blockIdx.y;
    const int newflat = (flat & 7) * 256 + (flat >> 3);
    const int qtile   = newflat & 31;
    const int bh      = newflat >> 5;

    const float* Qg = Q + (size_t)bh * SEQ * DHEAD + (size_t)(qtile * QBLK) * DHEAD;
    float*       Og = O + (size_t)bh * SEQ * DHEAD + (size_t)(qtile * QBLK) * DHEAD;

    // ---- Q fragments (fp16). Frag layout: idx=lane&15, k=(lane>>4)*8+i
    f16x8 qf[4];
    {
        const float* qrow = Qg + (size_t)(wave * 16 + lg) * DHEAD;
        #pragma unroll
        for (int dc = 0; dc < 4; ++dc) {
            const int d0 = dc * 32 + g * 8;
            float4 f0 = *(const float4*)(qrow + d0);
            float4 f1 = *(const float4*)(qrow + d0 + 4);
            qf[dc][0] = (_Float16)f0.x; qf[dc][1] = (_Float16)f0.y;
            qf[dc][2] = (_Float16)f0.z; qf[dc][3] = (_Float16)f0.w;
            qf[dc][4] = (_Float16)f1.x; qf[dc][5] = (_Float16)f1.y;
            qf[dc][6] = (_Float16)f1.z; qf[dc][7] = (_Float16)f1.w;
        }
    }

    f32x4 acc[8];
    #pragma unroll
    for (int dt = 0; dt < 8; ++dt) { acc[dt][0]=0.f; acc[dt][1]=0.f; acc[dt][2]=0.f; acc[dt][3]=0.f; }
    float m = -1e30f, l = 0.f;

    for (int t = 0; t < SEQ / KVBLK; ++t) {
        // ---- stage K+V: 8 global_load_lds dwordx4 per wave (1KB each), zero VALU
        {
            const _Float16* Ktile = Kp + (size_t)(bh * 32 + t) * (KVBLK * DHEAD);
            const _Float16* Vtile = Vp + (size_t)(bh * 32 + t) * (KVBLK * DHEAD);
            #pragma unroll
            for (int i = 0; i < 4; ++i) {
                const int eoff = wave * 2048 + i * 512;          // elements (1KB per call)
                __builtin_amdgcn_global_load_lds(AS1P(Ktile + eoff + lane * 8),
                                                 AS3P(&K_lds[eoff]), 16, 0, 0);
                __builtin_amdgcn_global_load_lds(AS1P(Vtile + eoff + lane * 8),
                                                 AS3P(&V_lds[eoff]), 16, 0, 0);
            }
        }
        __syncthreads();   // compiler drains vmcnt before s_barrier

        // ---- S^T = mfma(K, Q): lane holds S[kv=ct*16+g*4+r][q-row=lg]
        f32x4 s[4];
        __builtin_amdgcn_s_setprio(1);
        #pragma unroll
        for (int ct = 0; ct < 4; ++ct) {
            f32x4 a; a[0]=0.f; a[1]=0.f; a[2]=0.f; a[3]=0.f;
            #pragma unroll
            for (int dc = 0; dc < 4; ++dc) {
                const int krow = ct * 16 + lg;
                const int off  = krow * 128 + ((dc * 32 + g * 8) ^ ((krow & 7) << 3));
                f16x8 kh = *(const f16x8*)&K_lds[off];
                a = __builtin_amdgcn_mfma_f32_16x16x32_f16(kh, qf[dc], a, 0, 0, 0);
            }
            s[ct] = a;
        }
        __builtin_amdgcn_s_setprio(0);

        // ---- online softmax: lane owns q-row lg; 15 VALU + 2 shfl
        float pmax = s[0][0];
        #pragma unroll
        for (int ct = 0; ct < 4; ++ct)
            #pragma unroll
            for (int r = 0; r < 4; ++r)
                pmax = fmaxf(pmax, s[ct][r]);
        pmax = fmaxf(pmax, __shfl_xor(pmax, 16));
        pmax = fmaxf(pmax, __shfl_xor(pmax, 32));
        const float mnew = fmaxf(m, pmax);
        const float sc   = __expf(m - mnew);
        m = mnew;
        float rs = 0.f;
        #pragma unroll
        for (int ct = 0; ct < 4; ++ct)
            #pragma unroll
            for (int r = 0; r < 4; ++r) {
                float p = __expf(s[ct][r] - mnew);
                s[ct][r] = p;
                rs += p;
            }
        rs += __shfl_xor(rs, 16);
        rs += __shfl_xor(rs, 32);
        l = l * sc + rs;

        // ---- rescale acc (row q=g*4+r; its sc lives at lane g*16 + q)
        #pragma unroll
        for (int r = 0; r < 4; ++r) {
            const float scr = __shfl(sc, g * 20 + r);
            #pragma unroll
            for (int dt = 0; dt < 8; ++dt) acc[dt][r] *= scr;
        }

        // ---- P -> LDS, stride 64 + XOR ^((lg&7)<<3): b64 writes 2-way (free)
        _Float16* pbase = &P_lds[wave * 16 * 64];
        #pragma unroll
        for (int ct = 0; ct < 4; ++ct) {
            f16x4 pk;
            pk[0] = (_Float16)s[ct][0]; pk[1] = (_Float16)s[ct][1];
            pk[2] = (_Float16)s[ct][2]; pk[3] = (_Float16)s[ct][3];
            *(f16x4*)&pbase[lg * 64 + ((ct * 16 + g * 4) ^ ((lg & 7) << 3))] = pk;
        }

        // ---- O += P * V  (P A-frag + V^T B-frag, both plain swizzled b128 reads)
        __builtin_amdgcn_s_setprio(1);
        #pragma unroll
        for (int kt = 0; kt < 2; ++kt) {
            const int koff = (kt * 32 + g * 8) ^ ((lg & 7) << 3);
            f16x8 pf = *(const f16x8*)&pbase[lg * 64 + koff];
            #pragma unroll
            for (int dt = 0; dt < 8; ++dt) {
                f16x8 vf = *(const f16x8*)&V_lds[(dt * 16 + lg) * 64 + koff];
                acc[dt] = __builtin_amdgcn_mfma_f32_16x16x32_f16(pf, vf, acc[dt], 0, 0, 0);
            }
        }
        __builtin_amdgcn_s_setprio(0);
        __syncthreads();
    }

    // ---- epilogue
    const float linv = 1.f / l;
    float inv[4];
    #pragma unroll
    for (int r = 0; r < 4; ++r) inv[r] = __shfl(linv, g * 20 + r);
    float* ob = Og + (size_t)(wave * 16) * DHEAD;
    #pragma unroll
    for (int dt = 0; dt < 8; ++dt)
        #pragma unroll
        for (int r = 0; r < 4; ++r)
            ob[(size_t)(g * 4 + r) * DHEAD + dt * 16 + lg] = acc[dt][r] * inv[r];
}

// ---------------- legacy (R9) kernel: fallback when ws too small ----------------
__global__ __launch_bounds__(256, 3)
void attn_fwd_legacy(const float* __restrict__ Q, const float* __restrict__ K,
                     const float* __restrict__ V, float* __restrict__ O) {
    __shared__ __align__(16) _Float16 K_lds[KVBLK * KPAD];
    __shared__ __align__(16) _Float16 V_lds[KVBLK * DHEAD];
    __shared__ __align__(16) _Float16 P_lds[4 * 16 * PPAD];

    const int tid  = threadIdx.x;
    const int lane = tid & 63;
    const int wave = tid >> 6;
    const int g    = lane >> 4;
    const int lg   = lane & 15;

    const int flat    = blockIdx.x + gridDim.x * blockIdx.y;
    const int newflat = (flat & 7) * 256 + (flat >> 3);
    const int qtile   = newflat & 31;
    const int bh      = newflat >> 5;

    const size_t base = (size_t)bh * SEQ * DHEAD;
    const float* Qg = Q + base + (size_t)(qtile * QBLK) * DHEAD;
    const float* Kg = K + base;
    const float* Vg = V + base;
    float*       Og = O + base + (size_t)(qtile * QBLK) * DHEAD;

    const unsigned trbase = (unsigned)(size_t)&V_lds[0] + (unsigned)(g * 2048 + lg * 8);

    f16x8 qf[4];
    {
        const float* qrow = Qg + (size_t)(wave * 16 + lg) * DHEAD;
        #pragma unroll
        for (int dc = 0; dc < 4; ++dc) {
            const int d0 = dc * 32 + g * 8;
            float4 f0 = *(const float4*)(qrow + d0);
            float4 f1 = *(const float4*)(qrow + d0 + 4);
            qf[dc][0] = (_Float16)f0.x; qf[dc][1] = (_Float16)f0.y;
            qf[dc][2] = (_Float16)f0.z; qf[dc][3] = (_Float16)f0.w;
            qf[dc][4] = (_Float16)f1.x; qf[dc][5] = (_Float16)f1.y;
            qf[dc][6] = (_Float16)f1.z; qf[dc][7] = (_Float16)f1.w;
        }
    }

    f32x4 acc[8];
    #pragma unroll
    for (int dt = 0; dt < 8; ++dt) { acc[dt][0]=0.f; acc[dt][1]=0.f; acc[dt][2]=0.f; acc[dt][3]=0.f; }
    float m = -1e30f, l = 0.f;

    for (int t = 0; t < SEQ / KVBLK; ++t) {
        {
            const float* Kt = Kg + (size_t)t * KVBLK * DHEAD;
            #pragma unroll
            for (int j = 0; j < 4; ++j) {
                const int c   = tid + 256 * j;
                const int row = c >> 4;
                const int dc  = (c & 15) * 8;
                float4 f0 = *(const float4*)(Kt + row * DHEAD + dc);
                float4 f1 = *(const float4*)(Kt + row * DHEAD + dc + 4);
                f16x8 vh;
                vh[0]=(_Float16)f0.x; vh[1]=(_Float16)f0.y; vh[2]=(_Float16)f0.z; vh[3]=(_Float16)f0.w;
                vh[4]=(_Float16)f1.x; vh[5]=(_Float16)f1.y; vh[6]=(_Float16)f1.z; vh[7]=(_Float16)f1.w;
                *(f16x8*)&K_lds[row * KPAD + dc] = vh;
            }
            const float* Vt = Vg + (size_t)t * KVBLK * DHEAD;
            #pragma unroll
            for (int j = 0; j < 4; ++j) {
                const int c   = tid + 256 * j;
                const int d8  = (c & 1) | (((c >> 3) & 7) << 1);
                const int row = ((c >> 1) & 3) | ((c >> 6) << 2);
                const int d0  = d8 * 8;
                float4 f0 = *(const float4*)(Vt + row * DHEAD + d0);
                float4 f1 = *(const float4*)(Vt + row * DHEAD + d0 + 4);
                f16x8 vv;
                vv[0]=(_Float16)f0.x; vv[1]=(_Float16)f0.y; vv[2]=(_Float16)f0.z; vv[3]=(_Float16)f0.w;
                vv[4]=(_Float16)f1.x; vv[5]=(_Float16)f1.y; vv[6]=(_Float16)f1.z; vv[7]=(_Float16)f1.w;
                const int st = (row >> 2) * 8 + (d0 >> 4);
                *(f16x8*)&V_lds[st * 64 + (row & 3) * 16 + (d0 & 15)] = vv;
            }
        }
        __syncthreads();

        f32x4 s[4];
        __builtin_amdgcn_s_setprio(1);
        #pragma unroll
        for (int ct = 0; ct < 4; ++ct) {
            f32x4 a; a[0]=0.f; a[1]=0.f; a[2]=0.f; a[3]=0.f;
            #pragma unroll
            for (int dc = 0; dc < 4; ++dc) {
                const int off = (ct * 16 + lg) * KPAD + dc * 32 + g * 8;
                f16x8 kh = *(const f16x8*)&K_lds[off];
                a = __builtin_amdgcn_mfma_f32_16x16x32_f16(kh, qf[dc], a, 0, 0, 0);
            }
            s[ct] = a;
        }
        __builtin_amdgcn_s_setprio(0);

        float pmax = s[0][0];
        #pragma unroll
        for (int ct = 0; ct < 4; ++ct)
            #pragma unroll
            for (int r = 0; r < 4; ++r)
                pmax = fmaxf(pmax, s[ct][r]);
        pmax = fmaxf(pmax, __shfl_xor(pmax, 16));
        pmax = fmaxf(pmax, __shfl_xor(pmax, 32));
        const float mnew = fmaxf(m, pmax);
        const float sc   = __expf(m - mnew);
        m = mnew;
        float rs = 0.f;
        #pragma unroll
        for (int ct = 0; ct < 4; ++ct)
            #pragma unroll
            for (int r = 0; r < 4; ++r) {
                float p = __expf(s[ct][r] - mnew);
                s[ct][r] = p;
                rs += p;
            }
        rs += __shfl_xor(rs, 16);
        rs += __shfl_xor(rs, 32);
        l = l * sc + rs;

        #pragma unroll
        for (int r = 0; r < 4; ++r) {
            const float scr = __shfl(sc, g * 20 + r);
            #pragma unroll
            for (int dt = 0; dt < 8; ++dt) acc[dt][r] *= scr;
        }

        _Float16* pbase = &P_lds[wave * 16 * PPAD];
        #pragma unroll
        for (int ct = 0; ct < 4; ++ct) {
            f16x4 pk;
            pk[0] = (_Float16)s[ct][0]; pk[1] = (_Float16)s[ct][1];
            pk[2] = (_Float16)s[ct][2]; pk[3] = (_Float16)s[ct][3];
            *(f16x4*)&pbase[lg * PPAD + ct * 16 + g * 4] = pk;
        }

        #pragma unroll
        for (int kt = 0; kt < 2; ++kt) {
            f16x8 pf = *(const f16x8*)&pbase[lg * PPAD + kt * 32 + g * 8];
            #pragma unroll
            for (int dp = 0; dp < 4; ++dp) {
                f16x4 a0, a1, b0, b1;
                asm volatile(
                    "ds_read_b64_tr_b16 %0, %4 offset:%5\n\t"
                    "ds_read_b64_tr_b16 %1, %4 offset:%6\n\t"
                    "ds_read_b64_tr_b16 %2, %4 offset:%7\n\t"
                    "ds_read_b64_tr_b16 %3, %4 offset:%8\n\t"
                    "s_waitcnt lgkmcnt(0)"
                    : "=&v"(a0), "=&v"(a1), "=&v"(b0), "=&v"(b1)
                    : "v"(trbase),
                      "i"(kt * 8192 + (dp * 2 + 0) * 128),
                      "i"(kt * 8192 + 1024 + (dp * 2 + 0) * 128),
                      "i"(kt * 8192 + (dp * 2 + 1) * 128),
                      "i"(kt * 8192 + 1024 + (dp * 2 + 1) * 128)
                    : "memory");
                __builtin_amdgcn_sched_barrier(0);
                f16x8 vf0 = __builtin_shufflevector(a0, a1, 0, 1, 2, 3, 4, 5, 6, 7);
                f16x8 vf1 = __builtin_shufflevector(b0, b1, 0, 1, 2, 3, 4, 5, 6, 7);
                __builtin_amdgcn_s_setprio(1);
                acc[dp * 2 + 0] = __builtin_amdgcn_mfma_f32_16x16x32_f16(pf, vf0, acc[dp * 2 + 0], 0, 0, 0);
                acc[dp * 2 + 1] = __builtin_amdgcn_mfma_f32_16x16x32_f16(pf, vf1, acc[dp * 2 + 1], 0, 0, 0);
                __builtin_amdgcn_s_setprio(0);
            }
        }
        __syncthreads();
    }

    const float linv = 1.f / l;
    float inv[4];
    #pragma unroll
    for (int r = 0; r < 4; ++r) inv[r] = __shfl(linv, g * 20 + r);
    float* ob = Og + (size_t)(wave * 16) * DHEAD;
    #pragma unroll
    for (int dt = 0; dt < 8; ++dt)
        #pragma unroll
        for (int r = 0; r < 4; ++r)
            ob[(size_t)(g * 4 + r) * DHEAD + dt * 16 + lg] = acc[dt][r] * inv[r];
}

extern "C" void kernel_launch(void* const* d_in, const int* in_sizes, int n_in,
                              void* d_out, int out_size, void* d_ws, size_t ws_size,
                              hipStream_t stream) {
    const float* q = (const float*)d_in[0];
    const float* k = (const float*)d_in[1];
    const float* v = (const float*)d_in[2];
    float* out = (float*)d_out;
    const int BH = in_sizes[0] / (SEQ * DHEAD);   // 64
    dim3 grid(SEQ / QBLK, BH);

    const size_t elems = (size_t)BH * SEQ * DHEAD;           // 16M
    const size_t need  = elems * 2 * sizeof(_Float16);       // 64 MB
    if (ws_size >= need) {
        _Float16* Kp = (_Float16*)d_ws;
        _Float16* Vp = Kp + elems;
        preconv_kernel<<<dim3(BH * (SEQ / KVBLK)), dim3(256), 0, stream>>>(k, v, Kp, Vp);
        attn_fwd_kernel<<<grid, dim3(256), 0, stream>>>(q, Kp, Vp, out);
    } else {
        attn_fwd_legacy<<<grid, dim3(256), 0, stream>>>(q, k, v, out);
    }
}

// Round 13
// 242.345 us; speedup vs baseline: 1.8839x; 1.0349x over previous
//
#include <hip/hip_runtime.h>
#include <hip/hip_bf16.h>

// Flash-attention forward, B=4 H=16 S=2048 D=128, fp32 in/out, no 1/sqrt(D) scale.
// Round 12: T13 defer-max (RESCALE_THRESHOLD=8) — skip the acc-rescale pass,
//   sc-exp and broadcast shuffles when the tile max doesn't raise the running max
//   by >8 (wave-uniform __all). P bounded by e^8 (fits fp16), l by 2048*e^8 (f32).
//   Otherwise identical to R11 (pre-pass K swz / V^T swz, gload_lds staging,
//   swapped-operand QK^T softmax, XCD-gather, all-b128 LDS reads).

#define QBLK   64
#define KVBLK  64
#define DHEAD  128
#define SEQ    2048
#define KPAD   136   // legacy kernel only
#define PPAD   72    // legacy kernel only
#define RESCALE_THR 8.0f

typedef _Float16 f16x8 __attribute__((ext_vector_type(8)));
typedef _Float16 f16x4 __attribute__((ext_vector_type(4)));
typedef float    f32x4 __attribute__((ext_vector_type(4)));

#define AS1P(x) ((const __attribute__((address_space(1))) void*)(size_t)(x))
#define AS3P(x) ((__attribute__((address_space(3))) void*)(unsigned long long)(unsigned)(size_t)(x))

// ---------------- pre-pass: fp32 -> fp16, LDS-linear tile layouts ----------------
__global__ __launch_bounds__(256)
void preconv_kernel(const float* __restrict__ K, const float* __restrict__ V,
                    _Float16* __restrict__ Kp, _Float16* __restrict__ Vp) {
    const int bt = blockIdx.x;                       // bh*32 + t (tiles contiguous)
    const size_t src = (size_t)bt * (KVBLK * DHEAD);
    const float* Kt = K + src;
    const float* Vt = V + src;
    _Float16* Ko = Kp + src;
    _Float16* Vo = Vp + src;
    #pragma unroll
    for (int j = 0; j < 4; ++j) {
        const int c = threadIdx.x + 256 * j;         // 0..1023
        // K: row-major [kv][d], XOR-swizzled at 8-element granule
        {
            const int row = c >> 4;
            const int d0  = (c & 15) * 8;
            float4 f0 = *(const float4*)(Kt + row * DHEAD + d0);
            float4 f1 = *(const float4*)(Kt + row * DHEAD + d0 + 4);
            f16x8 h;
            h[0]=(_Float16)f0.x; h[1]=(_Float16)f0.y; h[2]=(_Float16)f0.z; h[3]=(_Float16)f0.w;
            h[4]=(_Float16)f1.x; h[5]=(_Float16)f1.y; h[6]=(_Float16)f1.z; h[7]=(_Float16)f1.w;
            *(f16x8*)&Ko[row * 128 + (d0 ^ ((row & 7) << 3))] = h;
        }
        // V^T: [d][kv], kv-granule XOR-swizzled by d-row (read path == K path)
        {
            const int d   = c & 127;                 // coalesced across lanes per i
            const int kvg = c >> 7;                  // 0..7
            f16x8 h;
            #pragma unroll
            for (int i = 0; i < 8; ++i)
                h[i] = (_Float16)Vt[(kvg * 8 + i) * DHEAD + d];
            *(f16x8*)&Vo[d * 64 + ((kvg * 8) ^ ((d & 7) << 3))] = h;
        }
    }
}

// ---------------- main kernel: gload_lds staging, all-b128 LDS reads ----------------
__global__ __launch_bounds__(256, 3)
void attn_fwd_kernel(const float* __restrict__ Q, const _Float16* __restrict__ Kp,
                     const _Float16* __restrict__ Vp, float* __restrict__ O) {
    __shared__ __align__(16) _Float16 K_lds[KVBLK * DHEAD];   // [kv][d] + XOR swizzle
    __shared__ __align__(16) _Float16 V_lds[DHEAD * KVBLK];   // [d][kv] + XOR swizzle
    __shared__ __align__(16) _Float16 P_lds[4 * 16 * 64];     // stride 64 + XOR swizzle

    const int tid  = threadIdx.x;
    const int lane = tid & 63;
    const int wave = tid >> 6;
    const int g    = lane >> 4;
    const int lg   = lane & 15;

    // XCD-gather swizzle
    const int flat    = blockIdx.x + gridDim.x * blockIdx.y;
    const int newflat = (flat & 7) * 256 + (flat >> 3);
    const int qtile   = newflat & 31;
    const int bh      = newflat >> 5;

    const float* Qg = Q + (size_t)bh * SEQ * DHEAD + (size_t)(qtile * QBLK) * DHEAD;
    float*       Og = O + (size_t)bh * SEQ * DHEAD + (size_t)(qtile * QBLK) * DHEAD;

    // ---- Q fragments (fp16). Frag layout: idx=lane&15, k=(lane>>4)*8+i
    f16x8 qf[4];
    {
        const float* qrow = Qg + (size_t)(wave * 16 + lg) * DHEAD;
        #pragma unroll
        for (int dc = 0; dc < 4; ++dc) {
            const int d0 = dc * 32 + g * 8;
            float4 f0 = *(const float4*)(qrow + d0);
            float4 f1 = *(const float4*)(qrow + d0 + 4);
            qf[dc][0] = (_Float16)f0.x; qf[dc][1] = (_Float16)f0.y;
            qf[dc][2] = (_Float16)f0.z; qf[dc][3] = (_Float16)f0.w;
            qf[dc][4] = (_Float16)f1.x; qf[dc][5] = (_Float16)f1.y;
            qf[dc][6] = (_Float16)f1.z; qf[dc][7] = (_Float16)f1.w;
        }
    }

    f32x4 acc[8];
    #pragma unroll
    for (int dt = 0; dt < 8; ++dt) { acc[dt][0]=0.f; acc[dt][1]=0.f; acc[dt][2]=0.f; acc[dt][3]=0.f; }
    float m = -1e30f, l = 0.f;

    for (int t = 0; t < SEQ / KVBLK; ++t) {
        // ---- stage K+V: 8 global_load_lds dwordx4 per wave (1KB each), zero VALU
        {
            const _Float16* Ktile = Kp + (size_t)(bh * 32 + t) * (KVBLK * DHEAD);
            const _Float16* Vtile = Vp + (size_t)(bh * 32 + t) * (KVBLK * DHEAD);
            #pragma unroll
            for (int i = 0; i < 4; ++i) {
                const int eoff = wave * 2048 + i * 512;          // elements (1KB per call)
                __builtin_amdgcn_global_load_lds(AS1P(Ktile + eoff + lane * 8),
                                                 AS3P(&K_lds[eoff]), 16, 0, 0);
                __builtin_amdgcn_global_load_lds(AS1P(Vtile + eoff + lane * 8),
                                                 AS3P(&V_lds[eoff]), 16, 0, 0);
            }
        }
        __syncthreads();   // compiler drains vmcnt before s_barrier

        // ---- S^T = mfma(K, Q): lane holds S[kv=ct*16+g*4+r][q-row=lg]
        f32x4 s[4];
        __builtin_amdgcn_s_setprio(1);
        #pragma unroll
        for (int ct = 0; ct < 4; ++ct) {
            f32x4 a; a[0]=0.f; a[1]=0.f; a[2]=0.f; a[3]=0.f;
            #pragma unroll
            for (int dc = 0; dc < 4; ++dc) {
                const int krow = ct * 16 + lg;
                const int off  = krow * 128 + ((dc * 32 + g * 8) ^ ((krow & 7) << 3));
                f16x8 kh = *(const f16x8*)&K_lds[off];
                a = __builtin_amdgcn_mfma_f32_16x16x32_f16(kh, qf[dc], a, 0, 0, 0);
            }
            s[ct] = a;
        }
        __builtin_amdgcn_s_setprio(0);

        // ---- online softmax with T13 defer-max: lane owns q-row lg
        float pmax = s[0][0];
        #pragma unroll
        for (int ct = 0; ct < 4; ++ct)
            #pragma unroll
            for (int r = 0; r < 4; ++r)
                pmax = fmaxf(pmax, s[ct][r]);
        pmax = fmaxf(pmax, __shfl_xor(pmax, 16));
        pmax = fmaxf(pmax, __shfl_xor(pmax, 32));

        if (!__all(pmax - m <= RESCALE_THR)) {
            // rare path: genuinely larger max -> rescale acc and l
            const float mnew = fmaxf(m, pmax);
            const float sc   = __expf(m - mnew);
            m = mnew;
            l *= sc;
            #pragma unroll
            for (int r = 0; r < 4; ++r) {
                const float scr = __shfl(sc, g * 20 + r);
                #pragma unroll
                for (int dt = 0; dt < 8; ++dt) acc[dt][r] *= scr;
            }
        }
        // common path: P = exp(S - m), bounded by e^THR
        float rs = 0.f;
        #pragma unroll
        for (int ct = 0; ct < 4; ++ct)
            #pragma unroll
            for (int r = 0; r < 4; ++r) {
                float p = __expf(s[ct][r] - m);
                s[ct][r] = p;
                rs += p;
            }
        rs += __shfl_xor(rs, 16);
        rs += __shfl_xor(rs, 32);
        l += rs;

        // ---- P -> LDS, stride 64 + XOR ^((lg&7)<<3): b64 writes 2-way (free)
        _Float16* pbase = &P_lds[wave * 16 * 64];
        #pragma unroll
        for (int ct = 0; ct < 4; ++ct) {
            f16x4 pk;
            pk[0] = (_Float16)s[ct][0]; pk[1] = (_Float16)s[ct][1];
            pk[2] = (_Float16)s[ct][2]; pk[3] = (_Float16)s[ct][3];
            *(f16x4*)&pbase[lg * 64 + ((ct * 16 + g * 4) ^ ((lg & 7) << 3))] = pk;
        }

        // ---- O += P * V  (P A-frag + V^T B-frag, both plain swizzled b128 reads)
        __builtin_amdgcn_s_setprio(1);
        #pragma unroll
        for (int kt = 0; kt < 2; ++kt) {
            const int koff = (kt * 32 + g * 8) ^ ((lg & 7) << 3);
            f16x8 pf = *(const f16x8*)&pbase[lg * 64 + koff];
            #pragma unroll
            for (int dt = 0; dt < 8; ++dt) {
                f16x8 vf = *(const f16x8*)&V_lds[(dt * 16 + lg) * 64 + koff];
                acc[dt] = __builtin_amdgcn_mfma_f32_16x16x32_f16(pf, vf, acc[dt], 0, 0, 0);
            }
        }
        __builtin_amdgcn_s_setprio(0);
        __syncthreads();
    }

    // ---- epilogue
    const float linv = 1.f / l;
    float inv[4];
    #pragma unroll
    for (int r = 0; r < 4; ++r) inv[r] = __shfl(linv, g * 20 + r);
    float* ob = Og + (size_t)(wave * 16) * DHEAD;
    #pragma unroll
    for (int dt = 0; dt < 8; ++dt)
        #pragma unroll
        for (int r = 0; r < 4; ++r)
            ob[(size_t)(g * 4 + r) * DHEAD + dt * 16 + lg] = acc[dt][r] * inv[r];
}

// ---------------- legacy (R9) kernel: fallback when ws too small ----------------
__global__ __launch_bounds__(256, 3)
void attn_fwd_legacy(const float* __restrict__ Q, const float* __restrict__ K,
                     const float* __restrict__ V, float* __restrict__ O) {
    __shared__ __align__(16) _Float16 K_lds[KVBLK * KPAD];
    __shared__ __align__(16) _Float16 V_lds[KVBLK * DHEAD];
    __shared__ __align__(16) _Float16 P_lds[4 * 16 * PPAD];

    const int tid  = threadIdx.x;
    const int lane = tid & 63;
    const int wave = tid >> 6;
    const int g    = lane >> 4;
    const int lg   = lane & 15;

    const int flat    = blockIdx.x + gridDim.x * blockIdx.y;
    const int newflat = (flat & 7) * 256 + (flat >> 3);
    const int qtile   = newflat & 31;
    const int bh      = newflat >> 5;

    const size_t base = (size_t)bh * SEQ * DHEAD;
    const float* Qg = Q + base + (size_t)(qtile * QBLK) * DHEAD;
    const float* Kg = K + base;
    const float* Vg = V + base;
    float*       Og = O + base + (size_t)(qtile * QBLK) * DHEAD;

    const unsigned trbase = (unsigned)(size_t)&V_lds[0] + (unsigned)(g * 2048 + lg * 8);

    f16x8 qf[4];
    {
        const float* qrow = Qg + (size_t)(wave * 16 + lg) * DHEAD;
        #pragma unroll
        for (int dc = 0; dc < 4; ++dc) {
            const int d0 = dc * 32 + g * 8;
            float4 f0 = *(const float4*)(qrow + d0);
            float4 f1 = *(const float4*)(qrow + d0 + 4);
            qf[dc][0] = (_Float16)f0.x; qf[dc][1] = (_Float16)f0.y;
            qf[dc][2] = (_Float16)f0.z; qf[dc][3] = (_Float16)f0.w;
            qf[dc][4] = (_Float16)f1.x; qf[dc][5] = (_Float16)f1.y;
            qf[dc][6] = (_Float16)f1.z; qf[dc][7] = (_Float16)f1.w;
        }
    }

    f32x4 acc[8];
    #pragma unroll
    for (int dt = 0; dt < 8; ++dt) { acc[dt][0]=0.f; acc[dt][1]=0.f; acc[dt][2]=0.f; acc[dt][3]=0.f; }
    float m = -1e30f, l = 0.f;

    for (int t = 0; t < SEQ / KVBLK; ++t) {
        {
            const float* Kt = Kg + (size_t)t * KVBLK * DHEAD;
            #pragma unroll
            for (int j = 0; j < 4; ++j) {
                const int c   = tid + 256 * j;
                const int row = c >> 4;
                const int dc  = (c & 15) * 8;
                float4 f0 = *(const float4*)(Kt + row * DHEAD + dc);
                float4 f1 = *(const float4*)(Kt + row * DHEAD + dc + 4);
                f16x8 vh;
                vh[0]=(_Float16)f0.x; vh[1]=(_Float16)f0.y; vh[2]=(_Float16)f0.z; vh[3]=(_Float16)f0.w;
                vh[4]=(_Float16)f1.x; vh[5]=(_Float16)f1.y; vh[6]=(_Float16)f1.z; vh[7]=(_Float16)f1.w;
                *(f16x8*)&K_lds[row * KPAD + dc] = vh;
            }
            const float* Vt = Vg + (size_t)t * KVBLK * DHEAD;
            #pragma unroll
            for (int j = 0; j < 4; ++j) {
                const int c   = tid + 256 * j;
                const int d8  = (c & 1) | (((c >> 3) & 7) << 1);
                const int row = ((c >> 1) & 3) | ((c >> 6) << 2);
                const int d0  = d8 * 8;
                float4 f0 = *(const float4*)(Vt + row * DHEAD + d0);
                float4 f1 = *(const float4*)(Vt + row * DHEAD + d0 + 4);
                f16x8 vv;
                vv[0]=(_Float16)f0.x; vv[1]=(_Float16)f0.y; vv[2]=(_Float16)f0.z; vv[3]=(_Float16)f0.w;
                vv[4]=(_Float16)f1.x; vv[5]=(_Float16)f1.y; vv[6]=(_Float16)f1.z; vv[7]=(_Float16)f1.w;
                const int st = (row >> 2) * 8 + (d0 >> 4);
                *(f16x8*)&V_lds[st * 64 + (row & 3) * 16 + (d0 & 15)] = vv;
            }
        }
        __syncthreads();

        f32x4 s[4];
        __builtin_amdgcn_s_setprio(1);
        #pragma unroll
        for (int ct = 0; ct < 4; ++ct) {
            f32x4 a; a[0]=0.f; a[1]=0.f; a[2]=0.f; a[3]=0.f;
            #pragma unroll
            for (int dc = 0; dc < 4; ++dc) {
                const int off = (ct * 16 + lg) * KPAD + dc * 32 + g * 8;
                f16x8 kh = *(const f16x8*)&K_lds[off];
                a = __builtin_amdgcn_mfma_f32_16x16x32_f16(kh, qf[dc], a, 0, 0, 0);
            }
            s[ct] = a;
        }
        __builtin_amdgcn_s_setprio(0);

        float pmax = s[0][0];
        #pragma unroll
        for (int ct = 0; ct < 4; ++ct)
            #pragma unroll
            for (int r = 0; r < 4; ++r)
                pmax = fmaxf(pmax, s[ct][r]);
        pmax = fmaxf(pmax, __shfl_xor(pmax, 16));
        pmax = fmaxf(pmax, __shfl_xor(pmax, 32));
        const float mnew = fmaxf(m, pmax);
        const float sc   = __expf(m - mnew);
        m = mnew;
        float rs = 0.f;
        #pragma unroll
        for (int ct = 0; ct < 4; ++ct)
            #pragma unroll
            for (int r = 0; r < 4; ++r) {
                float p = __expf(s[ct][r] - mnew);
                s[ct][r] = p;
                rs += p;
            }
        rs += __shfl_xor(rs, 16);
        rs += __shfl_xor(rs, 32);
        l = l * sc + rs;

        #pragma unroll
        for (int r = 0; r < 4; ++r) {
            const float scr = __shfl(sc, g * 20 + r);
            #pragma unroll
            for (int dt = 0; dt < 8; ++dt) acc[dt][r] *= scr;
        }

        _Float16* pbase = &P_lds[wave * 16 * PPAD];
        #pragma unroll
        for (int ct = 0; ct < 4; ++ct) {
            f16x4 pk;
            pk[0] = (_Float16)s[ct][0]; pk[1] = (_Float16)s[ct][1];
            pk[2] = (_Float16)s[ct][2]; pk[3] = (_Float16)s[ct][3];
            *(f16x4*)&pbase[lg * PPAD + ct * 16 + g * 4] = pk;
        }

        #pragma unroll
        for (int kt = 0; kt < 2; ++kt) {
            f16x8 pf = *(const f16x8*)&pbase[lg * PPAD + kt * 32 + g * 8];
            #pragma unroll
            for (int dp = 0; dp < 4; ++dp) {
                f16x4 a0, a1, b0, b1;
                asm volatile(
                    "ds_read_b64_tr_b16 %0, %4 offset:%5\n\t"
                    "ds_read_b64_tr_b16 %1, %4 offset:%6\n\t"
                    "ds_read_b64_tr_b16 %2, %4 offset:%7\n\t"
                    "ds_read_b64_tr_b16 %3, %4 offset:%8\n\t"
                    "s_waitcnt lgkmcnt(0)"
                    : "=&v"(a0), "=&v"(a1), "=&v"(b0), "=&v"(b1)
                    : "v"(trbase),
                      "i"(kt * 8192 + (dp * 2 + 0) * 128),
                      "i"(kt * 8192 + 1024 + (dp * 2 + 0) * 128),
                      "i"(kt * 8192 + (dp * 2 + 1) * 128),
                      "i"(kt * 8192 + 1024 + (dp * 2 + 1) * 128)
                    : "memory");
                __builtin_amdgcn_sched_barrier(0);
                f16x8 vf0 = __builtin_shufflevector(a0, a1, 0, 1, 2, 3, 4, 5, 6, 7);
                f16x8 vf1 = __builtin_shufflevector(b0, b1, 0, 1, 2, 3, 4, 5, 6, 7);
                __builtin_amdgcn_s_setprio(1);
                acc[dp * 2 + 0] = __builtin_amdgcn_mfma_f32_16x16x32_f16(pf, vf0, acc[dp * 2 + 0], 0, 0, 0);
                acc[dp * 2 + 1] = __builtin_amdgcn_mfma_f32_16x16x32_f16(pf, vf1, acc[dp * 2 + 1], 0, 0, 0);
                __builtin_amdgcn_s_setprio(0);
            }
        }
        __syncthreads();
    }

    const float linv = 1.f / l;
    float inv[4];
    #pragma unroll
    for (int r = 0; r < 4; ++r) inv[r] = __shfl(linv, g * 20 + r);
    float* ob = Og + (size_t)(wave * 16) * DHEAD;
    #pragma unroll
    for (int dt = 0; dt < 8; ++dt)
        #pragma unroll
        for (int r = 0; r < 4; ++r)
            ob[(size_t)(g * 4 + r) * DHEAD + dt * 16 + lg] = acc[dt][r] * inv[r];
}

extern "C" void kernel_launch(void* const* d_in, const int* in_sizes, int n_in,
                              void* d_out, int out_size, void* d_ws, size_t ws_size,
                              hipStream_t stream) {
    const float* q = (const float*)d_in[0];
    const float* k = (const float*)d_in[1];
    const float* v = (const float*)d_in[2];
    float* out = (float*)d_out;
    const int BH = in_sizes[0] / (SEQ * DHEAD);   // 64
    dim3 grid(SEQ / QBLK, BH);

    const size_t elems = (size_t)BH * SEQ * DHEAD;           // 16M
    const size_t need  = elems * 2 * sizeof(_Float16);       // 64 MB
    if (ws_size >= need) {
        _Float16* Kp = (_Float16*)d_ws;
        _Float16* Vp = Kp + elems;
        preconv_kernel<<<dim3(BH * (SEQ / KVBLK)), dim3(256), 0, stream>>>(k, v, Kp, Vp);
        attn_fwd_kernel<<<grid, dim3(256), 0, stream>>>(q, Kp, Vp, out);
    } else {
        attn_fwd_legacy<<<grid, dim3(256), 0, stream>>>(q, k, v, out);
    }
}